// Round 12
// baseline (311.852 us; speedup 1.0000x reference)
//
#include <hip/hip_runtime.h>
#include <hip/hip_bf16.h>

// EdgeConv B=8,C=64,N=4096,OUT=64,K=20.
// h[b,o,n,k] = z[b,n,o] - y[b,idx_k,o];  out = leakyrelu((z - min/max_k y)*inv + bias)
#define NN 4096
#define KK 20
#define LL 12        // per-thread sorted list of GROUP keys (group = 4 consecutive m)
#define NCAND 192    // 16 lists * LL group keys per row
#define EXTRG 24     // groups merged out before rescore (exact: bearing groups are top-<=20)
#define NF 24        // fp64-rescored finalists

typedef short bf16x8 __attribute__((ext_vector_type(8)));
typedef float f32x4  __attribute__((ext_vector_type(4)));

__device__ __forceinline__ unsigned umax_(unsigned a, unsigned b){ return a > b ? a : b; }
__device__ __forceinline__ unsigned umin_(unsigned a, unsigned b){ return a < b ? a : b; }

__device__ __forceinline__ unsigned bfbits(float f) {   // fp32 -> bf16 bits, RNE
    unsigned u = __float_as_uint(f);
    return (u + 0x7FFFu + ((u >> 16) & 1u)) >> 16;
}
__device__ __forceinline__ float bflo(unsigned u){ return __builtin_bit_cast(float, u << 16); }
__device__ __forceinline__ float bfhi(unsigned u){ return __builtin_bit_cast(float, u & 0xFFFF0000u); }

__device__ __forceinline__ uint4 packfrag_u(float4 lo, float4 hi) {
    return make_uint4(bfbits(lo.x) | (bfbits(lo.y) << 16),
                      bfbits(lo.z) | (bfbits(lo.w) << 16),
                      bfbits(hi.x) | (bfbits(hi.y) << 16),
                      bfbits(hi.z) | (bfbits(hi.w) << 16));
}

// ---- DPP cross-lane (row = 16 lanes; row_ror:n = 0x120+n) -------------------
template<int CTRL>
__device__ __forceinline__ int dpp_mov(int v) {
    return __builtin_amdgcn_update_dpp(0, v, CTRL, 0xF, 0xF, true);
}
template<int CTRL>
__device__ __forceinline__ float dpp_addf(float v) {
    return v + __builtin_bit_cast(float, dpp_mov<CTRL>(__builtin_bit_cast(int, v)));
}
template<int CTRL>
__device__ __forceinline__ unsigned dpp_maxu(unsigned v) {
    return umax_(v, (unsigned)dpp_mov<CTRL>((int)v));
}
__device__ __forceinline__ float rowsum16(float v) {
    v = dpp_addf<0x128>(v); v = dpp_addf<0x124>(v);
    v = dpp_addf<0x122>(v); v = dpp_addf<0x121>(v);
    return v;
}
__device__ __forceinline__ unsigned rowmax16(unsigned v) {
    v = dpp_maxu<0x128>(v); v = dpp_maxu<0x124>(v);
    v = dpp_maxu<0x122>(v); v = dpp_maxu<0x121>(v);
    return v;
}

// ---------------- Kernel 1: prep (re-gridded 4x: 1024 blocks, 32 rows/block) ----------
// 128 threads: q = tid>>5 owns channels q*16..+16 of row rl = tid&31.
__global__ __launch_bounds__(128) void k_prep(
    const float* __restrict__ x, const float* __restrict__ W,
    float* __restrict__ xt, unsigned short* __restrict__ xbf,
    unsigned short* __restrict__ ybf, unsigned short* __restrict__ zbf,
    double* __restrict__ xxd, float* __restrict__ xxc)
{
    __shared__ __align__(16) uint4  WfS[1024];    // 16384 B W fragments
    __shared__ __align__(16) float  tS32[32*68];  //  8704 B (bf16 stage aliases this)
    __shared__ double xxS[32*4];                  //  1024 B
    unsigned* bU = (unsigned*)tS32;               // bf16 rows, pitch 36 dwords

    int tid = threadIdx.x;
    int q = tid >> 5, rl = tid & 31;
    int b   = blockIdx.x & 7;
    int nb0 = (int)(blockIdx.x >> 3) << 5;
    int n   = nb0 + rl;
    size_t brow = (size_t)b * NN;

    // pack W fragments -> LDS; layout (o*16 + sel*4 + quad)
    {
        const float4* W4 = (const float4*)W;       // W row = 32 float4
        #pragma unroll
        for (int i = 0; i < 8; ++i) {
            int idx = i*128 + tid;                 // 0..1023
            int o = idx >> 4, sel = (idx >> 2) & 3, quad = idx & 3;
            float4 lo = W4[(size_t)o*32 + sel*8 + quad*2];
            float4 hi = W4[(size_t)o*32 + sel*8 + quad*2 + 1];
            WfS[idx] = packfrag_u(lo, hi);
        }
    }

    float xv[16];
    double xxp = 0.0;
    #pragma unroll
    for (int cc = 0; cc < 16; ++cc) {
        float v = x[((size_t)(b*64 + q*16 + cc) << 12) + n];
        xv[cc] = v;
        xxp += (double)v * (double)v;
    }
    xxS[rl*4 + q] = xxp;

    // fp32 stage -> coalesced xt stores
    #pragma unroll
    for (int cc = 0; cc < 16; ++cc) tS32[rl*68 + q*16 + cc] = xv[cc];
    __syncthreads();
    if (tid < 32) {
        double xx = ((xxS[tid*4] + xxS[tid*4+1]) + (xxS[tid*4+2] + xxS[tid*4+3]));
        xxd[brow + nb0 + tid] = xx;
        xxc[brow + nb0 + tid] = 1024.f - (float)xx;
    }
    {
        const float4* t4 = (const float4*)tS32;
        #pragma unroll
        for (int i = 0; i < 4; ++i) {
            int idx = i*128 + tid;                 // 0..511 float4s
            int r = idx >> 4, c4 = idx & 15;
            *(float4*)(xt + (brow + nb0 + r)*64 + 4*c4) = t4[r*17 + c4];
        }
    }
    __syncthreads();

    // bf16 stage (aliases tS32) -> coalesced xbf stores + y/z MFMA
    {
        unsigned pk[8];
        #pragma unroll
        for (int i = 0; i < 8; ++i)
            pk[i] = bfbits(xv[2*i]) | (bfbits(xv[2*i+1]) << 16);
        #pragma unroll
        for (int i = 0; i < 8; ++i) bU[rl*36 + q*8 + i] = pk[i];
    }
    __syncthreads();
    {
        const uint4* b4 = (const uint4*)bU;
        uint4* xb4 = (uint4*)xbf;
        #pragma unroll
        for (int i = 0; i < 2; ++i) {
            int idx = i*128 + tid;                 // 0..255 uint4s
            int r = idx >> 3, u4 = idx & 7;
            xb4[(brow + nb0 + r)*8 + u4] = b4[r*9 + u4];
        }
    }
    // y/z MFMA: wave w handles 16-row tile w (no further LDS writes)
    {
        int w = tid >> 6, lane = tid & 63, quad = lane >> 4, c = lane & 15;
        const uint4* b4 = (const uint4*)bU;
        int lrow = w*16 + c;
        bf16x8 bb0 = __builtin_bit_cast(bf16x8, b4[lrow*9 + quad]);
        bf16x8 bb1 = __builtin_bit_cast(bf16x8, b4[lrow*9 + 4 + quad]);
        int nw = nb0 + lrow;
        #pragma unroll 1
        for (int ot = 0; ot < 4; ++ot) {
            const uint4* wf = WfS + (ot*16 + c)*16 + quad;
            bf16x8 w1a = __builtin_bit_cast(bf16x8, wf[0]);
            bf16x8 w1b = __builtin_bit_cast(bf16x8, wf[4]);
            bf16x8 w2a = __builtin_bit_cast(bf16x8, wf[8]);
            bf16x8 w2b = __builtin_bit_cast(bf16x8, wf[12]);
            f32x4 acc1 = __builtin_amdgcn_mfma_f32_16x16x32_bf16(
                w1a, bb0, (f32x4){0.f,0.f,0.f,0.f}, 0, 0, 0);
            acc1 = __builtin_amdgcn_mfma_f32_16x16x32_bf16(w1b, bb1, acc1, 0, 0, 0);
            f32x4 acc2 = __builtin_amdgcn_mfma_f32_16x16x32_bf16(
                w2a, bb0, (f32x4){0.f,0.f,0.f,0.f}, 0, 0, 0);
            acc2 = __builtin_amdgcn_mfma_f32_16x16x32_bf16(w2b, bb1, acc2, 0, 0, 0);
            float z0 = acc1[0]+acc2[0], z1 = acc1[1]+acc2[1],
                  z2 = acc1[2]+acc2[2], z3 = acc1[3]+acc2[3];
            size_t obase = (brow + nw) * 64 + (ot*16 + quad*4);
            *(uint2*)(ybf + obase) = make_uint2(
                bfbits(acc1[0]) | (bfbits(acc1[1]) << 16),
                bfbits(acc1[2]) | (bfbits(acc1[3]) << 16));
            *(uint2*)(zbf + obase) = make_uint2(
                bfbits(z0) | (bfbits(z1) << 16),
                bfbits(z2) | (bfbits(z3) << 16));
        }
    }
}

// ---------------- Kernel 2: Gram + top-12 group keys -> global (ZERO LDS) ----------------
// 2048 blocks x 256, 16-n tile, b = blockIdx&7 (XCD affinity, matches k_refine).
__global__ __launch_bounds__(256, 4) void k_gram(
    const unsigned short* __restrict__ xbf, const float* __restrict__ xxc,
    unsigned* __restrict__ cand)
{
    int tid  = threadIdx.x;
    int w    = tid >> 6, lane = tid & 63;
    int quad = lane >> 4, c = lane & 15;
    int b  = blockIdx.x & 7;
    int n0 = (int)(blockIdx.x >> 3) << 4;
    size_t brow = (size_t)b * NN;

    const uint4* xb = (const uint4*)xbf;     // one row = 8 uint4

    size_t nrow = (brow + n0 + c) * 8 + quad;
    bf16x8 bn0 = __builtin_bit_cast(bf16x8, xb[nrow]);
    bf16x8 bn1 = __builtin_bit_cast(bf16x8, xb[nrow + 4]);

    unsigned keys[LL];
    #pragma unroll
    for (int i = 0; i < LL; ++i) keys[i] = 0u;

    // A stream, prefetch depth 2
    size_t abase = (brow + 16*w + c) * 8 + quad;
    size_t xxb   = brow + 16*w + quad*4;
    uint4  a0p[2], a1p[2];
    float4 xxp[2];
    a0p[0] = xb[abase];       a1p[0] = xb[abase + 4];
    a0p[1] = xb[abase + 512]; a1p[1] = xb[abase + 516];
    xxp[0] = *(const float4*)(xxc + xxb);
    xxp[1] = *(const float4*)(xxc + xxb + 64);

    #pragma unroll 2
    for (int chunk = 0; chunk < 64; ++chunk) {
        int s = chunk & 1;
        uint4 ca0 = a0p[s], ca1 = a1p[s];
        float4 x4 = xxp[s];
        if (chunk < 62) {
            size_t nb = abase + (size_t)(chunk + 2) * 512;
            a0p[s] = xb[nb]; a1p[s] = xb[nb + 4];
            xxp[s] = *(const float4*)(xxc + xxb + (chunk + 2)*64);
        }
        f32x4 acc = __builtin_amdgcn_mfma_f32_16x16x32_bf16(
            __builtin_bit_cast(bf16x8, ca0), bn0, (f32x4){0.f,0.f,0.f,0.f}, 0, 0, 0);
        acc = __builtin_amdgcn_mfma_f32_16x16x32_bf16(
            __builtin_bit_cast(bf16x8, ca1), bn1, acc, 0, 0, 0);

        float s0 = fmaf(2.f, acc[0], x4.x), s1 = fmaf(2.f, acc[1], x4.y);
        float s2 = fmaf(2.f, acc[2], x4.z), s3 = fmaf(2.f, acc[3], x4.w);
        float gm = fmaxf(fmaxf(s0, s1), fmaxf(s2, s3));
        unsigned key = (__float_as_uint(gm) & 0xFFFFFC00u)
                     | (unsigned)((chunk << 4) | (w << 2) | quad);
        #pragma unroll
        for (int t = 0; t < LL; ++t) {
            unsigned mx = umax_(keys[t], key);
            key = umin_(keys[t], key);
            keys[t] = mx;
        }
    }

    unsigned* cp = cand + ((size_t)(brow + n0 + c)) * NCAND + (w*4 + quad) * LL;
    ((uint4*)cp)[0] = make_uint4(keys[0], keys[1], keys[2],  keys[3]);
    ((uint4*)cp)[1] = make_uint4(keys[4], keys[5], keys[6],  keys[7]);
    ((uint4*)cp)[2] = make_uint4(keys[8], keys[9], keys[10], keys[11]);
}

// ---------------- Kernel 3: refine (2048 blocks, 16 rows, ~10 KB LDS) ----------------
__global__ __launch_bounds__(256, 4) void k_refine(
    const unsigned* __restrict__ cand,
    const unsigned short* __restrict__ xbf, const float* __restrict__ xt,
    const double* __restrict__ xxd, const float* __restrict__ xxc,
    const unsigned short* __restrict__ ybf, const unsigned short* __restrict__ zbf,
    const float* __restrict__ gamma, const float* __restrict__ beta,
    const float* __restrict__ rmean, const float* __restrict__ rvar,
    float* __restrict__ out)
{
    __shared__ __align__(16) unsigned gselS[16 * EXTRG];  // 1536 B
    __shared__ unsigned short m26S[16 * NF];              //  768 B
    __shared__ double   d26S[16 * NF];                    // 3072 B
    __shared__ unsigned short selS[16 * KK];              //  640 B
    __shared__ float    outS[64 * 17];                    // 4352 B

    int tid = threadIdx.x;
    int r = tid >> 4, g = tid & 15;
    int b  = blockIdx.x & 7;
    int n0 = (int)(blockIdx.x >> 3) << 4;
    int n  = n0 + r;
    size_t brow = (size_t)b * NN;

    // stage 1: own sorted 12-list from cand -> registers
    unsigned mk[LL];
    {
        const uint4* ks = (const uint4*)(cand + ((size_t)(brow + n)) * NCAND + g * LL);
        uint4 k0 = ks[0], k1 = ks[1], k2 = ks[2];
        mk[0]=k0.x; mk[1]=k0.y; mk[2]=k0.z;  mk[3]=k0.w;
        mk[4]=k1.x; mk[5]=k1.y; mk[6]=k1.z;  mk[7]=k1.w;
        mk[8]=k2.x; mk[9]=k2.y; mk[10]=k2.z; mk[11]=k2.w;
    }
    uint2 anb = *(const uint2*)(xbf + (brow + n) * 64 + 4*g);
    float an0 = bflo(anb.x), an1 = bfhi(anb.x),
          an2 = bflo(anb.y), an3 = bfhi(anb.y);

    // stage 2: pop-shift merge of 16 sorted lists -> top-EXTRG groups
    #pragma unroll 1
    for (int it = 0; it < EXTRG; ++it) {
        unsigned vm = rowmax16(mk[0]);
        bool win = (mk[0] == vm);
        #pragma unroll
        for (int q = 0; q < LL-1; ++q) mk[q] = win ? mk[q+1] : mk[q];
        mk[LL-1] = win ? 0u : mk[LL-1];
        if (g == (it & 15)) gselS[r*EXTRG + it] = vm;
    }

    // stage 3: bf16 cooperative rescore of 96 candidates
    unsigned myk[6];
    #pragma unroll
    for (int j = 0; j < 6; ++j) {
        uint4 Gj = *(const uint4*)(gselS + r*EXTRG + 4*j);
        unsigned gk4[4] = {Gj.x, Gj.y, Gj.z, Gj.w};
        #pragma unroll
        for (int h = 0; h < 2; ++h) {
            uint2 vbs[8]; float xxm[8];
            #pragma unroll
            for (int u = 0; u < 8; ++u) {
                int t = h*8 + u;
                int m = (int)((gk4[t >> 2] & 1023u) << 2) | (t & 3);
                vbs[u] = *(const uint2*)(xbf + (brow + m) * 64 + 4*g);
                xxm[u] = xxc[brow + m];
            }
            #pragma unroll
            for (int u = 0; u < 8; ++u) {
                int t = h*8 + u;
                float p = an0 * bflo(vbs[u].x);
                p = fmaf(an1, bfhi(vbs[u].x), p);
                p = fmaf(an2, bflo(vbs[u].y), p);
                p = fmaf(an3, bfhi(vbs[u].y), p);
                p = rowsum16(p);
                float sc = fmaf(2.f, p, xxm[u]);
                unsigned key = (__float_as_uint(sc) & 0xFFFFFF80u) | (unsigned)(j*16 + t);
                if (t == g) myk[j] = key;
            }
        }
    }
    #pragma unroll
    for (int a = 1; a < 6; ++a)
        #pragma unroll
        for (int q = a; q > 0; --q) {
            unsigned lo = umin_(myk[q-1], myk[q]);
            myk[q-1] = umax_(myk[q-1], myk[q]);
            myk[q] = lo;
        }

    // stage 3.5: pop-shift merge -> exact top-NF of the 96 fp32 keys
    #pragma unroll 1
    for (int it = 0; it < NF; ++it) {
        unsigned vm = rowmax16(myk[0]);
        bool win = (myk[0] == vm);
        #pragma unroll
        for (int q = 0; q < 5; ++q) myk[q] = win ? myk[q+1] : myk[q];
        myk[5] = win ? 0u : myk[5];
        if (g == (it & 15)) {
            int i = (int)(vm & 127u);
            unsigned gk = gselS[r*EXTRG + (i >> 2)];
            m26S[r*NF + it] = (unsigned short)(((gk & 1023u) << 2) | (i & 3));
        }
    }

    // stage 4: fp64 per-lane full dots (lane = candidate), dual accumulators
    #pragma unroll
    for (int round = 0; round < 2; ++round) {
        int t = round*16 + g;
        if (t < NF) {
            int m = (int)m26S[r*NF + t];
            const float4* xm = (const float4*)(xt + (brow + m) * 64);
            const float4* xn = (const float4*)(xt + (brow + n) * 64);
            double acc0 = 0.0, acc1 = 0.0;
            #pragma unroll
            for (int i = 0; i < 8; ++i) {
                float4 v0 = xm[2*i], a0 = xn[2*i];
                float4 v1 = xm[2*i+1], a1 = xn[2*i+1];
                acc0 += (double)a0.x*(double)v0.x + (double)a0.y*(double)v0.y
                      + (double)a0.z*(double)v0.z + (double)a0.w*(double)v0.w;
                acc1 += (double)a1.x*(double)v1.x + (double)a1.y*(double)v1.y
                      + (double)a1.z*(double)v1.z + (double)a1.w*(double)v1.w;
            }
            d26S[r*NF + t] = 2.0*(acc0 + acc1) - xxd[brow + m];
        }
    }

    // stage 5: exact top-20 set by rank counting
    #pragma unroll
    for (int round = 0; round < 2; ++round) {
        int t = round*16 + g;
        if (t < NF) {
            double st = d26S[r*NF + t];
            int cnt = 0;
            #pragma unroll
            for (int p = 0; p < NF; ++p) cnt += (d26S[r*NF + p] > st) ? 1 : 0;
            if (cnt < KK) selS[r*KK + cnt] = m26S[r*NF + t];
        }
    }

    // stage 6: gather y (bf16), min/max per o, epilogue
    float mn[4] = { __builtin_inff(), __builtin_inff(), __builtin_inff(), __builtin_inff() };
    float mx[4] = { -__builtin_inff(), -__builtin_inff(), -__builtin_inff(), -__builtin_inff() };
    #pragma unroll
    for (int hb = 0; hb < 2; ++hb) {
        uint2 yb[10];
        #pragma unroll
        for (int k = 0; k < 10; ++k)
            yb[k] = *(const uint2*)(ybf + (brow + (int)selS[r*KK + hb*10 + k]) * 64 + 4*g);
        #pragma unroll
        for (int k = 0; k < 10; ++k) {
            float y0 = bflo(yb[k].x), y1 = bfhi(yb[k].x),
                  y2 = bflo(yb[k].y), y3 = bfhi(yb[k].y);
            mn[0] = fminf(mn[0], y0); mx[0] = fmaxf(mx[0], y0);
            mn[1] = fminf(mn[1], y1); mx[1] = fmaxf(mx[1], y1);
            mn[2] = fminf(mn[2], y2); mx[2] = fmaxf(mx[2], y2);
            mn[3] = fminf(mn[3], y3); mx[3] = fmaxf(mx[3], y3);
        }
    }
    uint2 zb = *(const uint2*)(zbf + (brow + n) * 64 + 4*g);
    float zz[4] = {bflo(zb.x), bfhi(zb.x), bflo(zb.y), bfhi(zb.y)};
    #pragma unroll
    for (int j = 0; j < 4; ++j) {
        int o = 4*g + j;
        float inv  = gamma[o] / sqrtf(rvar[o] + 1e-5f);
        float bias = beta[o] - rmean[o] * inv;
        float ysel = (inv >= 0.f) ? mn[j] : mx[j];
        float h = (zz[j] - ysel) * inv + bias;
        outS[o*17 + r] = (h >= 0.f) ? h : 0.2f * h;
    }
    __syncthreads();   // cross-wave: output transpose
    {
        int o = tid >> 2, q = tid & 3;
        const float* ob = outS + o*17;
        float4 v = make_float4(ob[4*q], ob[4*q + 1], ob[4*q + 2], ob[4*q + 3]);
        *(float4*)(out + ((size_t)(b*64 + o) << 12) + n0 + 4*q) = v;
    }
}

extern "C" void kernel_launch(void* const* d_in, const int* in_sizes, int n_in,
                              void* d_out, int out_size, void* d_ws, size_t ws_size,
                              hipStream_t stream) {
    const float* x     = (const float*)d_in[0];
    const float* W     = (const float*)d_in[1];
    const float* gamma = (const float*)d_in[2];
    const float* beta  = (const float*)d_in[3];
    const float* rmean = (const float*)d_in[4];
    const float* rvar  = (const float*)d_in[5];
    float* out = (float*)d_out;

    char* ws = (char*)d_ws;
    float*          xt   = (float*)          (ws);                          //  8 MB
    unsigned short* xbf  = (unsigned short*) (ws + ((size_t) 8 << 20));     //  4 MB
    unsigned short* ybf  = (unsigned short*) (ws + ((size_t)12 << 20));     //  4 MB
    unsigned short* zbf  = (unsigned short*) (ws + ((size_t)16 << 20));     //  4 MB
    double*         xxd  = (double*)         (ws + ((size_t)20 << 20));     // 256 KB
    float*          xxc  = (float*)          (ws + ((size_t)20 << 20) + (512 << 10)); // 128 KB
    unsigned*       cand = (unsigned*)       (ws + ((size_t)21 << 20));     // 24 MB

    k_prep  <<<1024, 128, 0, stream>>>(x, W, xt, xbf, ybf, zbf, xxd, xxc);
    k_gram  <<<2048, 256, 0, stream>>>(xbf, xxc, cand);
    k_refine<<<2048, 256, 0, stream>>>(cand, xbf, xt, xxd, xxc, ybf, zbf,
                                       gamma, beta, rmean, rvar, out);
}